// Round 12
// baseline (163.150 us; speedup 1.0000x reference)
//
#include <hip/hip_runtime.h>
#include <hip/hip_fp16.h>
#include <math.h>

#define WF 33
#define TSLAB 135168            // 33 wf * 64 h * 64 c complex per (b,t)
#define PBINS 270336            // 2 b * 33 wf * 64 fh * 64 c

// ---------------------------------------------------------------------------
// 8-point FFT in registers. DIR = -1 forward, +1 inverse.
// ---------------------------------------------------------------------------
template<int DIR>
__device__ __forceinline__ void fft8(float* fr, float* fi){
    const float r = 0.70710678118654752440f;
    float u0r=fr[0]+fr[4], u0i=fi[0]+fi[4];
    float v0r=fr[0]-fr[4], v0i=fi[0]-fi[4];
    float u1r=fr[1]+fr[5], u1i=fi[1]+fi[5];
    float v1r=fr[1]-fr[5], v1i=fi[1]-fi[5];
    float u2r=fr[2]+fr[6], u2i=fi[2]+fi[6];
    float v2r=fr[2]-fr[6], v2i=fi[2]-fi[6];
    float u3r=fr[3]+fr[7], u3i=fi[3]+fi[7];
    float v3r=fr[3]-fr[7], v3i=fi[3]-fi[7];
    float t;
    if (DIR < 0){
        t = r*(v1r + v1i); v1i = r*(v1i - v1r); v1r = t;
        t = v2i;           v2i = -v2r;          v2r = t;
        t = r*(v3i - v3r); v3i = -r*(v3r + v3i); v3r = t;
    } else {
        t = r*(v1r - v1i); v1i = r*(v1i + v1r); v1r = t;
        t = -v2i;          v2i = v2r;           v2r = t;
        t = -r*(v3r + v3i); v3i = r*(v3r - v3i); v3r = t;
    }
    float p0r=u0r+u2r, p0i=u0i+u2i, p1r=u1r+u3r, p1i=u1i+u3i;
    float q0r=u0r-u2r, q0i=u0i-u2i, q1r=u1r-u3r, q1i=u1i-u3i;
    if (DIR < 0){ t=q1i; q1i=-q1r; q1r=t; } else { t=-q1i; q1i=q1r; q1r=t; }
    fr[0]=p0r+p1r; fi[0]=p0i+p1i;
    fr[4]=p0r-p1r; fi[4]=p0i-p1i;
    fr[2]=q0r+q1r; fi[2]=q0i+q1i;
    fr[6]=q0r-q1r; fi[6]=q0i-q1i;
    p0r=v0r+v2r; p0i=v0i+v2i; p1r=v1r+v3r; p1i=v1i+v3i;
    q0r=v0r-v2r; q0i=v0i-v2i; q1r=v1r-v3r; q1i=v1i-v3i;
    if (DIR < 0){ t=q1i; q1i=-q1r; q1r=t; } else { t=-q1i; q1i=q1r; q1r=t; }
    fr[1]=p0r+p1r; fi[1]=p0i+p1i;
    fr[5]=p0r-p1r; fi[5]=p0i-p1i;
    fr[3]=q0r+q1r; fi[3]=q0i+q1i;
    fr[7]=q0r-q1r; fi[7]=q0i-q1i;
}

__device__ __forceinline__ void build_tw64(float* twr, float* twi, int tid){
    if (tid < 64){
        float ang = -6.28318530717958647692f * (float)tid * (1.0f/64.0f);
        float s, c;
        sincosf(ang, &s, &c);
        twr[tid] = c; twi[tid] = s;
    }
}

template<int DIR>
__device__ __forceinline__ void tw64_apply(float* fr, float* fi, int d,
                                           const float* twr, const float* twi){
    #pragma unroll
    for (int j = 1; j < 8; j++){
        int m = d * j;
        float wr = twr[m];
        float wi = (DIR < 0) ? twi[m] : -twi[m];
        float xr = fr[j], xi = fi[j];
        fr[j] = xr*wr - xi*wi;
        fi[j] = xr*wi + xi*wr;
    }
}

// ---------------------------------------------------------------------------
// K1: forward FFT along w. block=(bt,h). float staging and fp16 exchange
// share one 16KB LDS buffer -> 8 blocks/CU (32 waves, full occupancy).
// writes A2[bt][wf][h][c] fp16, wf=0..32.
// ---------------------------------------------------------------------------
__global__ __launch_bounds__(256) void k1_row_fwd(const float* __restrict__ x,
                                                  __half2* __restrict__ A2){
    __shared__ __align__(16) char smem[64*64*4];   // 16KB union
    __shared__ float twr[64], twi[64];
    float*   Sf = (float*)smem;
    __half2* S  = (__half2*)smem;
    int tid = threadIdx.x;
    int c = tid & 63, idx = tid >> 6;
    int blk = blockIdx.x;
    int h = blk & 63, bt = blk >> 6;

    build_tw64(twr, twi, tid);

    const float4* xp4 = (const float4*)(x + (((size_t)bt * 64 + h) << 12));
    #pragma unroll
    for (int q = 0; q < 4; q++)
        ((float4*)Sf)[tid + q*256] = xp4[tid + q*256];
    __syncthreads();

    float in0[8], in1[8];
    #pragma unroll
    for (int n1 = 0; n1 < 8; n1++){
        in0[n1] = Sf[(8*n1 + idx    )*64 + c];
        in1[n1] = Sf[(8*n1 + idx + 4)*64 + c];
    }
    __syncthreads();    // all staging reads done before exchange overwrites

    #pragma unroll
    for (int pass = 0; pass < 2; pass++){
        int n2 = idx + 4*pass;
        float fr[8], fi[8];
        #pragma unroll
        for (int n1 = 0; n1 < 8; n1++){
            fr[n1] = pass ? in1[n1] : in0[n1];
            fi[n1] = 0.f;
        }
        fft8<-1>(fr, fi);
        tw64_apply<-1>(fr, fi, n2, twr, twi);
        #pragma unroll
        for (int k1 = 0; k1 < 8; k1++)
            S[(8*n2 + k1)*64 + c] = __floats2half2_rn(fr[k1], fi[k1]);
    }
    __syncthreads();
    #pragma unroll
    for (int pass = 0; pass < 2; pass++){
        int k1 = idx + 4*pass;
        float fr[8], fi[8];
        #pragma unroll
        for (int n2 = 0; n2 < 8; n2++){
            float2 v = __half22float2(S[(8*n2 + k1)*64 + c]);
            fr[n2] = v.x; fi[n2] = v.y;
        }
        fft8<-1>(fr, fi);
        #pragma unroll
        for (int k2 = 0; k2 < 8; k2++){
            int wf = k1 + 8*k2;
            if (wf <= 32)
                A2[(((size_t)bt * WF + wf)*64 + h)*64 + c] =
                    __floats2half2_rn(fr[k2], fi[k2]);
        }
    }
}

// ---------------------------------------------------------------------------
// KA: per-chunk forward h-FFT + LOCAL scan (zero init), CARRY-ONLY output.
// A2 read-only. grid = 66*8cg*8chunk = 4224 single-wave blocks, 1 c/lane.
// Wave-private LDS exchange, no barriers.
// ---------------------------------------------------------------------------
__global__ __launch_bounds__(64) void kA(const float2* __restrict__ Khat,
                                         const __half2* __restrict__ A2,
                                         __half2* __restrict__ Lc){
    __shared__ float Sre[64*9], Sim[64*9];
    __shared__ float twr[64], twi[64];
    int tid = threadIdx.x;
    int c = tid & 7, k = tid >> 3;
    int u = blockIdx.x;
    int chunk = u & 7;
    int cg = (u >> 3) & 7;
    int wfb = u >> 6;                    // 0..65
    int wf = wfb % 33, b = wfb / 33;
    int c0 = cg*8 + c;

    build_tw64(twr, twi, tid);

    float Kr[8], Ki[8];
    {
        const float2* Kb = Khat + (size_t)wf*4096 + c0;
        #pragma unroll
        for (int k2 = 0; k2 < 8; k2++){
            float2 kv = Kb[(size_t)(k + 8*k2)*64];
            Kr[k2]=kv.x; Ki[k2]=kv.y;
        }
    }
    float Xr[8]={0,0,0,0,0,0,0,0}, Xi[8]={0,0,0,0,0,0,0,0};

    size_t sbase = ((size_t)(b*64 + chunk*8)*WF + wf)*4096;
    const size_t TS = TSLAB;

    __half2 pre[8];
    {
        const __half2* p = A2 + sbase + c0;
        #pragma unroll
        for (int n1 = 0; n1 < 8; n1++)
            pre[n1] = p[(size_t)(8*n1 + k)*64];
    }
    __syncthreads();   // twiddles ready (single wave: cheap)

    for (int d = 0; d < 8; d++){
        __half2 cur[8];
        #pragma unroll
        for (int i = 0; i < 8; i++) cur[i] = pre[i];
        if (d < 7){
            const __half2* p = A2 + sbase + (size_t)(d+1)*TS + c0;
            #pragma unroll
            for (int n1 = 0; n1 < 8; n1++)
                pre[n1] = p[(size_t)(8*n1 + k)*64];
        }
        float fr[8], fi[8];
        #pragma unroll
        for (int n1 = 0; n1 < 8; n1++){
            float2 v = __half22float2(cur[n1]);
            fr[n1]=v.x; fi[n1]=v.y;
        }
        fft8<-1>(fr,fi); tw64_apply<-1>(fr,fi,k,twr,twi);
        #pragma unroll
        for (int k1 = 0; k1 < 8; k1++){
            int row = (8*k + k1)*9 + c;
            Sre[row] = fr[k1]; Sim[row] = fi[k1];
        }
        #pragma unroll
        for (int n2 = 0; n2 < 8; n2++){
            int row = (8*n2 + k)*9 + c;
            fr[n2]=Sre[row]; fi[n2]=Sim[row];
        }
        fft8<-1>(fr,fi);
        #pragma unroll
        for (int k2 = 0; k2 < 8; k2++){
            float xr = Xr[k2], xi = Xi[k2];
            Xr[k2] = fmaf(Kr[k2], xr, fmaf(-Ki[k2], xi, fr[k2]));
            Xi[k2] = fmaf(Kr[k2], xi, fmaf( Ki[k2], xr, fi[k2]));
        }
    }
    __half2* Lb = Lc + (size_t)chunk*PBINS + ((size_t)b*WF + wf)*4096 + c0;
    #pragma unroll
    for (int k2 = 0; k2 < 8; k2++)
        Lb[(size_t)(k + 8*k2)*64] = __floats2half2_rn(Xr[k2], Xi[k2]);
}

// ---------------------------------------------------------------------------
// KC: full re-scan with INLINE carry combine (kB folded in).
// Seed X = F_{chunk-1}: F=0; for j<chunk: F = Lc[j] + K^8 * F.
// Then per t: fwd h-FFT(U), X=K*X+U, inverse h-FFT, *1/64, write A2 in place.
// grid = 4224 single-wave blocks, barrier-free exchange.
// ---------------------------------------------------------------------------
__global__ __launch_bounds__(64) void kC(const float2* __restrict__ Khat,
                                         const __half2* __restrict__ Lc,
                                         __half2* __restrict__ A2){
    __shared__ float Sre[64*9], Sim[64*9];
    __shared__ float twr[64], twi[64];
    int tid = threadIdx.x;
    int c = tid & 7, k = tid >> 3;
    int u = blockIdx.x;
    int chunk = u & 7;
    int cg = (u >> 3) & 7;
    int wfb = u >> 6;
    int wf = wfb % 33, b = wfb / 33;
    int c0 = cg*8 + c;

    build_tw64(twr, twi, tid);

    float Kr[8], Ki[8];
    {
        const float2* Kb = Khat + (size_t)wf*4096 + c0;
        #pragma unroll
        for (int k2 = 0; k2 < 8; k2++){
            float2 kv = Kb[(size_t)(k + 8*k2)*64];
            Kr[k2]=kv.x; Ki[k2]=kv.y;
        }
    }
    // inline carry combine (replaces kB + Cin buffer)
    float Xr[8], Xi[8];
    {
        const __half2* Lb = Lc + ((size_t)b*WF + wf)*4096 + c0;
        #pragma unroll
        for (int k2 = 0; k2 < 8; k2++){
            float kr = Kr[k2], ki = Ki[k2];
            #pragma unroll
            for (int i = 0; i < 3; i++){          // K^8
                float nr = kr*kr - ki*ki;
                float ni = 2.f*kr*ki;
                kr = nr; ki = ni;
            }
            float Fr = 0.f, Fi = 0.f;
            for (int j = 0; j < chunk; j++){
                float2 l = __half22float2(Lb[(size_t)j*PBINS + (size_t)(k + 8*k2)*64]);
                float nr = fmaf(kr, Fr, fmaf(-ki, Fi, l.x));
                float ni = fmaf(kr, Fi, fmaf( ki, Fr, l.y));
                Fr = nr; Fi = ni;
            }
            Xr[k2] = Fr; Xi[k2] = Fi;
        }
    }

    size_t sbase = ((size_t)(b*64 + chunk*8)*WF + wf)*4096;
    const size_t TS = TSLAB;

    __half2 pre[8];
    {
        const __half2* p = A2 + sbase + c0;
        #pragma unroll
        for (int n1 = 0; n1 < 8; n1++)
            pre[n1] = p[(size_t)(8*n1 + k)*64];
    }
    __syncthreads();   // twiddles ready

    for (int d = 0; d < 8; d++){
        size_t sl = sbase + (size_t)d*TS;
        __half2 cur[8];
        #pragma unroll
        for (int i = 0; i < 8; i++) cur[i] = pre[i];
        if (d < 7){
            const __half2* p = A2 + sl + TS + c0;
            #pragma unroll
            for (int n1 = 0; n1 < 8; n1++)
                pre[n1] = p[(size_t)(8*n1 + k)*64];
        }
        // ---- forward h-FFT of U slice ----
        float fr[8], fi[8];
        #pragma unroll
        for (int n1 = 0; n1 < 8; n1++){
            float2 v = __half22float2(cur[n1]);
            fr[n1]=v.x; fi[n1]=v.y;
        }
        fft8<-1>(fr,fi); tw64_apply<-1>(fr,fi,k,twr,twi);
        #pragma unroll
        for (int k1 = 0; k1 < 8; k1++){
            int row = (8*k + k1)*9 + c;
            Sre[row] = fr[k1]; Sim[row] = fi[k1];
        }
        #pragma unroll
        for (int n2 = 0; n2 < 8; n2++){
            int row = (8*n2 + k)*9 + c;
            fr[n2]=Sre[row]; fi[n2]=Sim[row];
        }
        fft8<-1>(fr,fi);
        // ---- scan: X = K*X + U_hat ----
        #pragma unroll
        for (int k2 = 0; k2 < 8; k2++){
            float xr = Xr[k2], xi = Xi[k2];
            Xr[k2] = fmaf(Kr[k2], xr, fmaf(-Ki[k2], xi, fr[k2]));
            Xi[k2] = fmaf(Kr[k2], xi, fmaf( Ki[k2], xr, fi[k2]));
        }
        // ---- inverse h-FFT (unnormalized/64) ----
        #pragma unroll
        for (int i = 0; i < 8; i++){ fr[i]=Xr[i]; fi[i]=Xi[i]; }
        fft8<1>(fr,fi); tw64_apply<1>(fr,fi,k,twr,twi);
        #pragma unroll
        for (int h1 = 0; h1 < 8; h1++){
            int row = (8*h1 + k)*9 + c;
            Sre[row] = fr[h1]; Sim[row] = fi[h1];
        }
        #pragma unroll
        for (int k1 = 0; k1 < 8; k1++){
            int row = (8*k + k1)*9 + c;
            fr[k1]=Sre[row]; fi[k1]=Sim[row];
        }
        fft8<1>(fr,fi);
        const float sc = 1.0f/64.0f;
        __half2* sp = A2 + sl + c0;
        #pragma unroll
        for (int h2 = 0; h2 < 8; h2++)
            sp[(size_t)(k + 8*h2)*64] = __floats2half2_rn(fr[h2]*sc, fi[h2]*sc);
    }
}

// ---------------------------------------------------------------------------
// K5: inverse FFT along w + Hermitian + final 1/64 scale. block=(bt,h).
// fp16 LDS exchange -> 16.5KB LDS -> full occupancy.
// ---------------------------------------------------------------------------
__global__ __launch_bounds__(256) void k5_row_inv(const __half2* __restrict__ A2,
                                                  float* __restrict__ out){
    __shared__ __half2 S[64*64];       // 16KB
    __shared__ float twr[64], twi[64];
    int tid = threadIdx.x;
    int c = tid & 63, idx = tid >> 6;
    int blk = blockIdx.x;
    int h = blk & 63, bt = blk >> 6;

    build_tw64(twr, twi, tid);
    __syncthreads();

    const __half2* base = A2 + (size_t)bt * TSLAB;   // [wf][h][c]
    #pragma unroll
    for (int pass = 0; pass < 2; pass++){
        int n2 = idx + 4*pass;
        float fr[8], fi[8];
        #pragma unroll
        for (int n1 = 0; n1 < 8; n1++){
            int n = 8*n1 + n2;
            float2 v;
            if (n <= 32){
                v = __half22float2(base[((size_t)n*64 + h)*64 + c]);
            } else {
                v = __half22float2(base[((size_t)(64 - n)*64 + h)*64 + c]);
                v.y = -v.y;
            }
            fr[n1] = v.x; fi[n1] = v.y;
        }
        fft8<1>(fr, fi);
        tw64_apply<1>(fr, fi, n2, twr, twi);
        #pragma unroll
        for (int k1 = 0; k1 < 8; k1++)
            S[(8*n2 + k1)*64 + c] = __floats2half2_rn(fr[k1], fi[k1]);
    }
    __syncthreads();
    float* op = out + (((size_t)bt * 64 + h) << 12);
    const float scale = 1.0f / 64.0f;
    #pragma unroll
    for (int pass = 0; pass < 2; pass++){
        int k1 = idx + 4*pass;
        float fr[8], fi[8];
        #pragma unroll
        for (int n2 = 0; n2 < 8; n2++){
            float2 v = __half22float2(S[(8*n2 + k1)*64 + c]);
            fr[n2] = v.x; fi[n2] = v.y;
        }
        fft8<1>(fr, fi);
        #pragma unroll
        for (int k2 = 0; k2 < 8; k2++)
            op[(k1 + 8*k2)*64 + c] = fr[k2] * scale;
    }
}

// ---------------------------------------------------------------------------
// K0: K_hat (tiny) — radix-2 LDS FFT. Layout Khat[(wf*64 + fh)*64 + c], fp32.
// ---------------------------------------------------------------------------
__device__ __forceinline__ int bitrev6(int i){
    return ((i&1)<<5) | ((i&2)<<3) | ((i&4)<<1) | ((i&8)>>1) | ((i&16)>>3) | ((i&32)>>5);
}

template<int SPT, int SB>
__device__ void fft64_all(float* __restrict__ re, float* __restrict__ im,
                          const float* __restrict__ twr, const float* __restrict__ twi,
                          int tid){
    __syncthreads();
    #pragma unroll
    for (int q = 0; q < 16; q++){
        int idx = tid + q*256;
        int i = idx >> 6, r = idx & 63;
        int j = bitrev6(i);
        if (i < j){
            int a = i*SPT + r*SB, b = j*SPT + r*SB;
            float t0 = re[a]; re[a] = re[b]; re[b] = t0;
            float t1 = im[a]; im[a] = im[b]; im[b] = t1;
        }
    }
    __syncthreads();
    for (int s = 1; s <= 6; s++){
        int half = 1 << (s-1);
        #pragma unroll
        for (int q = 0; q < 8; q++){
            int flat = tid + q*256;
            int kk = flat >> 6;
            int r = flat & 63;
            int j = kk & (half-1);
            int group = kk >> (s-1);
            int i0 = (group << s) + j;
            int i1 = i0 + half;
            int twidx = j << (6 - s);
            float wr = twr[twidx], wi = twi[twidx];
            int a0 = i0*SPT + r*SB, a1 = i1*SPT + r*SB;
            float xr = re[a1], xi = im[a1];
            float vr = xr*wr - xi*wi;
            float vi = xr*wi + xi*wr;
            float u0r = re[a0], u0i = im[a0];
            re[a0] = u0r + vr; im[a0] = u0i + vi;
            re[a1] = u0r - vr; im[a1] = u0i - vi;
        }
        __syncthreads();
    }
}

__global__ __launch_bounds__(256) void khat_kernel(const float* __restrict__ ker,
                                                   float2* __restrict__ Khat){
    __shared__ float re[64*65];
    __shared__ float im[64*65];
    __shared__ float twr[64], twi[64];
    int tid = threadIdx.x;
    int c = blockIdx.x;

    build_tw64(twr, twi, tid);
    #pragma unroll
    for (int q = 0; q < 16; q++){
        int idx = tid + q*256;
        re[(idx>>6)*65 + (idx&63)] = 0.f;
        im[(idx>>6)*65 + (idx&63)] = 0.f;
    }
    __syncthreads();
    for (int idx = tid; idx < 225; idx += 256){
        int i = idx / 15, j = idx - i*15;
        re[(24+i)*65 + (24+j)] = ker[c*225 + idx];
    }
    fft64_all<1,65>(re, im, twr, twi, tid);
    fft64_all<65,1>(re, im, twr, twi, tid);

    for (int idx = tid; idx < 64*WF; idx += 256){
        int fh = idx / WF, wf = idx - fh*WF;
        Khat[((size_t)wf*64 + fh)*64 + c] = make_float2(re[fh*65 + wf], im[fh*65 + wf]);
    }
}

// ---------------------------------------------------------------------------
extern "C" void kernel_launch(void* const* d_in, const int* in_sizes, int n_in,
                              void* d_out, int out_size, void* d_ws, size_t ws_size,
                              hipStream_t stream)
{
    const float* x   = (const float*)d_in[0];   // (2,64,64,64,64)
    const float* ker = (const float*)d_in[1];   // (64,15,15)
    float* out = (float*)d_out;                 // (2,64,64,64,64)

    char* ws = (char*)d_ws;
    float2*  Khat = (float2*)ws;                            //  1,081,344 B
    __half2* A2   = (__half2*)(ws + 1081344);               // 69,206,016 B
    __half2* Lc   = (__half2*)(ws + 1081344 + 69206016);    //  8,650,752 B

    khat_kernel<<<64, 256, 0, stream>>>(ker, Khat);
    k1_row_fwd<<<8192, 256, 0, stream>>>(x, A2);
    kA<<<4224, 64, 0, stream>>>(Khat, A2, Lc);
    kC<<<4224, 64, 0, stream>>>(Khat, Lc, A2);
    k5_row_inv<<<8192, 256, 0, stream>>>(A2, out);
}

// Round 13
// 155.374 us; speedup vs baseline: 1.0500x; 1.0500x over previous
//
#include <hip/hip_runtime.h>
#include <hip/hip_fp16.h>
#include <math.h>

#define WF 33
#define TSLAB 135168            // 33 wf * 64 h * 64 c complex per (b,t)
#define PBINS 270336            // 2 b * 33 wf * 64 fh * 64 c

// ---------------------------------------------------------------------------
// 8-point FFT in registers. DIR = -1 forward, +1 inverse.
// ---------------------------------------------------------------------------
template<int DIR>
__device__ __forceinline__ void fft8(float* fr, float* fi){
    const float r = 0.70710678118654752440f;
    float u0r=fr[0]+fr[4], u0i=fi[0]+fi[4];
    float v0r=fr[0]-fr[4], v0i=fi[0]-fi[4];
    float u1r=fr[1]+fr[5], u1i=fi[1]+fi[5];
    float v1r=fr[1]-fr[5], v1i=fi[1]-fi[5];
    float u2r=fr[2]+fr[6], u2i=fi[2]+fi[6];
    float v2r=fr[2]-fr[6], v2i=fi[2]-fi[6];
    float u3r=fr[3]+fr[7], u3i=fi[3]+fi[7];
    float v3r=fr[3]-fr[7], v3i=fi[3]-fi[7];
    float t;
    if (DIR < 0){
        t = r*(v1r + v1i); v1i = r*(v1i - v1r); v1r = t;
        t = v2i;           v2i = -v2r;          v2r = t;
        t = r*(v3i - v3r); v3i = -r*(v3r + v3i); v3r = t;
    } else {
        t = r*(v1r - v1i); v1i = r*(v1i + v1r); v1r = t;
        t = -v2i;          v2i = v2r;           v2r = t;
        t = -r*(v3r + v3i); v3i = r*(v3r - v3i); v3r = t;
    }
    float p0r=u0r+u2r, p0i=u0i+u2i, p1r=u1r+u3r, p1i=u1i+u3i;
    float q0r=u0r-u2r, q0i=u0i-u2i, q1r=u1r-u3r, q1i=u1i-u3i;
    if (DIR < 0){ t=q1i; q1i=-q1r; q1r=t; } else { t=-q1i; q1i=q1r; q1r=t; }
    fr[0]=p0r+p1r; fi[0]=p0i+p1i;
    fr[4]=p0r-p1r; fi[4]=p0i-p1i;
    fr[2]=q0r+q1r; fi[2]=q0i+q1i;
    fr[6]=q0r-q1r; fi[6]=q0i-q1i;
    p0r=v0r+v2r; p0i=v0i+v2i; p1r=v1r+v3r; p1i=v1i+v3i;
    q0r=v0r-v2r; q0i=v0i-v2i; q1r=v1r-v3r; q1i=v1i-v3i;
    if (DIR < 0){ t=q1i; q1i=-q1r; q1r=t; } else { t=-q1i; q1i=q1r; q1r=t; }
    fr[1]=p0r+p1r; fi[1]=p0i+p1i;
    fr[5]=p0r-p1r; fi[5]=p0i-p1i;
    fr[3]=q0r+q1r; fi[3]=q0i+q1i;
    fr[7]=q0r-q1r; fi[7]=q0i-q1i;
}

__device__ __forceinline__ void build_tw64(float* twr, float* twi, int tid){
    if (tid < 64){
        float ang = -6.28318530717958647692f * (float)tid * (1.0f/64.0f);
        float s, c;
        sincosf(ang, &s, &c);
        twr[tid] = c; twi[tid] = s;
    }
}

template<int DIR>
__device__ __forceinline__ void tw64_apply(float* fr, float* fi, int d,
                                           const float* twr, const float* twi){
    #pragma unroll
    for (int j = 1; j < 8; j++){
        int m = d * j;
        float wr = twr[m];
        float wi = (DIR < 0) ? twi[m] : -twi[m];
        float xr = fr[j], xi = fi[j];
        fr[j] = xr*wr - xi*wi;
        fi[j] = xr*wi + xi*wr;
    }
}

// ---------------------------------------------------------------------------
// K1: forward FFT along w. block=(bt,h). float staging and fp16 exchange
// share one 16KB LDS buffer -> 8 blocks/CU (32 waves).
// writes A2[bt][wf][h][c] fp16, wf=0..32.
// ---------------------------------------------------------------------------
__global__ __launch_bounds__(256) void k1_row_fwd(const float* __restrict__ x,
                                                  __half2* __restrict__ A2){
    __shared__ __align__(16) char smem[64*64*4];   // 16KB union
    __shared__ float twr[64], twi[64];
    float*   Sf = (float*)smem;
    __half2* S  = (__half2*)smem;
    int tid = threadIdx.x;
    int c = tid & 63, idx = tid >> 6;
    int blk = blockIdx.x;
    int h = blk & 63, bt = blk >> 6;

    build_tw64(twr, twi, tid);

    const float4* xp4 = (const float4*)(x + (((size_t)bt * 64 + h) << 12));
    #pragma unroll
    for (int q = 0; q < 4; q++)
        ((float4*)Sf)[tid + q*256] = xp4[tid + q*256];
    __syncthreads();

    float in0[8], in1[8];
    #pragma unroll
    for (int n1 = 0; n1 < 8; n1++){
        in0[n1] = Sf[(8*n1 + idx    )*64 + c];
        in1[n1] = Sf[(8*n1 + idx + 4)*64 + c];
    }
    __syncthreads();    // all staging reads done before exchange overwrites

    #pragma unroll
    for (int pass = 0; pass < 2; pass++){
        int n2 = idx + 4*pass;
        float fr[8], fi[8];
        #pragma unroll
        for (int n1 = 0; n1 < 8; n1++){
            fr[n1] = pass ? in1[n1] : in0[n1];
            fi[n1] = 0.f;
        }
        fft8<-1>(fr, fi);
        tw64_apply<-1>(fr, fi, n2, twr, twi);
        #pragma unroll
        for (int k1 = 0; k1 < 8; k1++)
            S[(8*n2 + k1)*64 + c] = __floats2half2_rn(fr[k1], fi[k1]);
    }
    __syncthreads();
    #pragma unroll
    for (int pass = 0; pass < 2; pass++){
        int k1 = idx + 4*pass;
        float fr[8], fi[8];
        #pragma unroll
        for (int n2 = 0; n2 < 8; n2++){
            float2 v = __half22float2(S[(8*n2 + k1)*64 + c]);
            fr[n2] = v.x; fi[n2] = v.y;
        }
        fft8<-1>(fr, fi);
        #pragma unroll
        for (int k2 = 0; k2 < 8; k2++){
            int wf = k1 + 8*k2;
            if (wf <= 32)
                A2[(((size_t)bt * WF + wf)*64 + h)*64 + c] =
                    __floats2half2_rn(fr[k2], fi[k2]);
        }
    }
}

// ---------------------------------------------------------------------------
// KA: per-chunk forward h-FFT + LOCAL scan (zero init), CARRY-ONLY output.
// A2 read-only. grid = 66*8cg*8chunk = 4224 single-wave blocks, 1 c/lane.
// Wave-private LDS exchange, no barriers.
// ---------------------------------------------------------------------------
__global__ __launch_bounds__(64) void kA(const float2* __restrict__ Khat,
                                         const __half2* __restrict__ A2,
                                         __half2* __restrict__ Lc){
    __shared__ float Sre[64*9], Sim[64*9];
    __shared__ float twr[64], twi[64];
    int tid = threadIdx.x;
    int c = tid & 7, k = tid >> 3;
    int u = blockIdx.x;
    int chunk = u & 7;
    int cg = (u >> 3) & 7;
    int wfb = u >> 6;                    // 0..65
    int wf = wfb % 33, b = wfb / 33;
    int c0 = cg*8 + c;

    build_tw64(twr, twi, tid);

    float Kr[8], Ki[8];
    {
        const float2* Kb = Khat + (size_t)wf*4096 + c0;
        #pragma unroll
        for (int k2 = 0; k2 < 8; k2++){
            float2 kv = Kb[(size_t)(k + 8*k2)*64];
            Kr[k2]=kv.x; Ki[k2]=kv.y;
        }
    }
    float Xr[8]={0,0,0,0,0,0,0,0}, Xi[8]={0,0,0,0,0,0,0,0};

    size_t sbase = ((size_t)(b*64 + chunk*8)*WF + wf)*4096;
    const size_t TS = TSLAB;

    __half2 pre[8];
    {
        const __half2* p = A2 + sbase + c0;
        #pragma unroll
        for (int n1 = 0; n1 < 8; n1++)
            pre[n1] = p[(size_t)(8*n1 + k)*64];
    }
    __syncthreads();   // twiddles ready (single wave: cheap)

    for (int d = 0; d < 8; d++){
        __half2 cur[8];
        #pragma unroll
        for (int i = 0; i < 8; i++) cur[i] = pre[i];
        if (d < 7){
            const __half2* p = A2 + sbase + (size_t)(d+1)*TS + c0;
            #pragma unroll
            for (int n1 = 0; n1 < 8; n1++)
                pre[n1] = p[(size_t)(8*n1 + k)*64];
        }
        float fr[8], fi[8];
        #pragma unroll
        for (int n1 = 0; n1 < 8; n1++){
            float2 v = __half22float2(cur[n1]);
            fr[n1]=v.x; fi[n1]=v.y;
        }
        fft8<-1>(fr,fi); tw64_apply<-1>(fr,fi,k,twr,twi);
        #pragma unroll
        for (int k1 = 0; k1 < 8; k1++){
            int row = (8*k + k1)*9 + c;
            Sre[row] = fr[k1]; Sim[row] = fi[k1];
        }
        #pragma unroll
        for (int n2 = 0; n2 < 8; n2++){
            int row = (8*n2 + k)*9 + c;
            fr[n2]=Sre[row]; fi[n2]=Sim[row];
        }
        fft8<-1>(fr,fi);
        #pragma unroll
        for (int k2 = 0; k2 < 8; k2++){
            float xr = Xr[k2], xi = Xi[k2];
            Xr[k2] = fmaf(Kr[k2], xr, fmaf(-Ki[k2], xi, fr[k2]));
            Xi[k2] = fmaf(Kr[k2], xi, fmaf( Ki[k2], xr, fi[k2]));
        }
    }
    __half2* Lb = Lc + (size_t)chunk*PBINS + ((size_t)b*WF + wf)*4096 + c0;
    #pragma unroll
    for (int k2 = 0; k2 < 8; k2++)
        Lb[(size_t)(k + 8*k2)*64] = __floats2half2_rn(Xr[k2], Xi[k2]);
}

// ---------------------------------------------------------------------------
// KB: sequential 8-chunk combine per bin. F_j = L_j + K^8 F_{j-1}; Cin_j=F_{j-1}.
// Fully coalesced; Cin fp16.
// ---------------------------------------------------------------------------
__global__ __launch_bounds__(256) void kB(const float2* __restrict__ Khat,
                                          const __half2* __restrict__ Lc,
                                          __half2* __restrict__ Cin){
    int g = blockIdx.x*256 + threadIdx.x;    // exactly PBINS threads
    int c = g & 63;
    int fh = (g >> 6) & 63;
    int rest = g >> 12;                      // b*33 + wf
    int wf = rest % 33;
    float2 K = Khat[((size_t)wf*64 + fh)*64 + c];
    float kr = K.x, ki = K.y;
    #pragma unroll
    for (int i = 0; i < 3; i++){             // K^8
        float nr = kr*kr - ki*ki;
        float ni = 2.f*kr*ki;
        kr = nr; ki = ni;
    }
    float Fr = 0.f, Fi = 0.f;
    #pragma unroll
    for (int j = 0; j < 8; j++){
        Cin[(size_t)j*PBINS + g] = __floats2half2_rn(Fr, Fi);
        float2 L = __half22float2(Lc[(size_t)j*PBINS + g]);
        float nr = fmaf(kr, Fr, fmaf(-ki, Fi, L.x));
        float ni = fmaf(kr, Fi, fmaf( ki, Fr, L.y));
        Fr = nr; Fi = ni;
    }
}

// ---------------------------------------------------------------------------
// KC: full re-scan with carry-in read once from Cin. Reads U from A2,
// fwd h-FFT, X=K*X+U seeded by Cin, inverse h-FFT, *1/64, write A2 in place.
// grid = 4224 single-wave blocks, barrier-free exchange.
// ---------------------------------------------------------------------------
__global__ __launch_bounds__(64) void kC(const float2* __restrict__ Khat,
                                         const __half2* __restrict__ Cin,
                                         __half2* __restrict__ A2){
    __shared__ float Sre[64*9], Sim[64*9];
    __shared__ float twr[64], twi[64];
    int tid = threadIdx.x;
    int c = tid & 7, k = tid >> 3;
    int u = blockIdx.x;
    int chunk = u & 7;
    int cg = (u >> 3) & 7;
    int wfb = u >> 6;
    int wf = wfb % 33, b = wfb / 33;
    int c0 = cg*8 + c;

    build_tw64(twr, twi, tid);

    float Kr[8], Ki[8];
    {
        const float2* Kb = Khat + (size_t)wf*4096 + c0;
        #pragma unroll
        for (int k2 = 0; k2 < 8; k2++){
            float2 kv = Kb[(size_t)(k + 8*k2)*64];
            Kr[k2]=kv.x; Ki[k2]=kv.y;
        }
    }
    float Xr[8], Xi[8];
    {
        const __half2* Cb = Cin + (size_t)chunk*PBINS + ((size_t)b*WF + wf)*4096 + c0;
        #pragma unroll
        for (int k2 = 0; k2 < 8; k2++){
            float2 v = __half22float2(Cb[(size_t)(k + 8*k2)*64]);
            Xr[k2]=v.x; Xi[k2]=v.y;
        }
    }

    size_t sbase = ((size_t)(b*64 + chunk*8)*WF + wf)*4096;
    const size_t TS = TSLAB;

    __half2 pre[8];
    {
        const __half2* p = A2 + sbase + c0;
        #pragma unroll
        for (int n1 = 0; n1 < 8; n1++)
            pre[n1] = p[(size_t)(8*n1 + k)*64];
    }
    __syncthreads();   // twiddles ready

    for (int d = 0; d < 8; d++){
        size_t sl = sbase + (size_t)d*TS;
        __half2 cur[8];
        #pragma unroll
        for (int i = 0; i < 8; i++) cur[i] = pre[i];
        if (d < 7){
            const __half2* p = A2 + sl + TS + c0;
            #pragma unroll
            for (int n1 = 0; n1 < 8; n1++)
                pre[n1] = p[(size_t)(8*n1 + k)*64];
        }
        // ---- forward h-FFT of U slice ----
        float fr[8], fi[8];
        #pragma unroll
        for (int n1 = 0; n1 < 8; n1++){
            float2 v = __half22float2(cur[n1]);
            fr[n1]=v.x; fi[n1]=v.y;
        }
        fft8<-1>(fr,fi); tw64_apply<-1>(fr,fi,k,twr,twi);
        #pragma unroll
        for (int k1 = 0; k1 < 8; k1++){
            int row = (8*k + k1)*9 + c;
            Sre[row] = fr[k1]; Sim[row] = fi[k1];
        }
        #pragma unroll
        for (int n2 = 0; n2 < 8; n2++){
            int row = (8*n2 + k)*9 + c;
            fr[n2]=Sre[row]; fi[n2]=Sim[row];
        }
        fft8<-1>(fr,fi);
        // ---- scan: X = K*X + U_hat ----
        #pragma unroll
        for (int k2 = 0; k2 < 8; k2++){
            float xr = Xr[k2], xi = Xi[k2];
            Xr[k2] = fmaf(Kr[k2], xr, fmaf(-Ki[k2], xi, fr[k2]));
            Xi[k2] = fmaf(Kr[k2], xi, fmaf( Ki[k2], xr, fi[k2]));
        }
        // ---- inverse h-FFT (unnormalized/64) ----
        #pragma unroll
        for (int i = 0; i < 8; i++){ fr[i]=Xr[i]; fi[i]=Xi[i]; }
        fft8<1>(fr,fi); tw64_apply<1>(fr,fi,k,twr,twi);
        #pragma unroll
        for (int h1 = 0; h1 < 8; h1++){
            int row = (8*h1 + k)*9 + c;
            Sre[row] = fr[h1]; Sim[row] = fi[h1];
        }
        #pragma unroll
        for (int k1 = 0; k1 < 8; k1++){
            int row = (8*k + k1)*9 + c;
            fr[k1]=Sre[row]; fi[k1]=Sim[row];
        }
        fft8<1>(fr,fi);
        const float sc = 1.0f/64.0f;
        __half2* sp = A2 + sl + c0;
        #pragma unroll
        for (int h2 = 0; h2 < 8; h2++)
            sp[(size_t)(k + 8*h2)*64] = __floats2half2_rn(fr[h2]*sc, fi[h2]*sc);
    }
}

// ---------------------------------------------------------------------------
// K5: inverse FFT along w + Hermitian + final 1/64 scale. block=(bt,h).
// fp16 LDS exchange -> 16.5KB LDS.
// ---------------------------------------------------------------------------
__global__ __launch_bounds__(256) void k5_row_inv(const __half2* __restrict__ A2,
                                                  float* __restrict__ out){
    __shared__ __half2 S[64*64];       // 16KB
    __shared__ float twr[64], twi[64];
    int tid = threadIdx.x;
    int c = tid & 63, idx = tid >> 6;
    int blk = blockIdx.x;
    int h = blk & 63, bt = blk >> 6;

    build_tw64(twr, twi, tid);
    __syncthreads();

    const __half2* base = A2 + (size_t)bt * TSLAB;   // [wf][h][c]
    #pragma unroll
    for (int pass = 0; pass < 2; pass++){
        int n2 = idx + 4*pass;
        float fr[8], fi[8];
        #pragma unroll
        for (int n1 = 0; n1 < 8; n1++){
            int n = 8*n1 + n2;
            float2 v;
            if (n <= 32){
                v = __half22float2(base[((size_t)n*64 + h)*64 + c]);
            } else {
                v = __half22float2(base[((size_t)(64 - n)*64 + h)*64 + c]);
                v.y = -v.y;
            }
            fr[n1] = v.x; fi[n1] = v.y;
        }
        fft8<1>(fr, fi);
        tw64_apply<1>(fr, fi, n2, twr, twi);
        #pragma unroll
        for (int k1 = 0; k1 < 8; k1++)
            S[(8*n2 + k1)*64 + c] = __floats2half2_rn(fr[k1], fi[k1]);
    }
    __syncthreads();
    float* op = out + (((size_t)bt * 64 + h) << 12);
    const float scale = 1.0f / 64.0f;
    #pragma unroll
    for (int pass = 0; pass < 2; pass++){
        int k1 = idx + 4*pass;
        float fr[8], fi[8];
        #pragma unroll
        for (int n2 = 0; n2 < 8; n2++){
            float2 v = __half22float2(S[(8*n2 + k1)*64 + c]);
            fr[n2] = v.x; fi[n2] = v.y;
        }
        fft8<1>(fr, fi);
        #pragma unroll
        for (int k2 = 0; k2 < 8; k2++)
            op[(k1 + 8*k2)*64 + c] = fr[k2] * scale;
    }
}

// ---------------------------------------------------------------------------
// K0: K_hat (tiny) — radix-2 LDS FFT. Layout Khat[(wf*64 + fh)*64 + c], fp32.
// ---------------------------------------------------------------------------
__device__ __forceinline__ int bitrev6(int i){
    return ((i&1)<<5) | ((i&2)<<3) | ((i&4)<<1) | ((i&8)>>1) | ((i&16)>>3) | ((i&32)>>5);
}

template<int SPT, int SB>
__device__ void fft64_all(float* __restrict__ re, float* __restrict__ im,
                          const float* __restrict__ twr, const float* __restrict__ twi,
                          int tid){
    __syncthreads();
    #pragma unroll
    for (int q = 0; q < 16; q++){
        int idx = tid + q*256;
        int i = idx >> 6, r = idx & 63;
        int j = bitrev6(i);
        if (i < j){
            int a = i*SPT + r*SB, b = j*SPT + r*SB;
            float t0 = re[a]; re[a] = re[b]; re[b] = t0;
            float t1 = im[a]; im[a] = im[b]; im[b] = t1;
        }
    }
    __syncthreads();
    for (int s = 1; s <= 6; s++){
        int half = 1 << (s-1);
        #pragma unroll
        for (int q = 0; q < 8; q++){
            int flat = tid + q*256;
            int kk = flat >> 6;
            int r = flat & 63;
            int j = kk & (half-1);
            int group = kk >> (s-1);
            int i0 = (group << s) + j;
            int i1 = i0 + half;
            int twidx = j << (6 - s);
            float wr = twr[twidx], wi = twi[twidx];
            int a0 = i0*SPT + r*SB, a1 = i1*SPT + r*SB;
            float xr = re[a1], xi = im[a1];
            float vr = xr*wr - xi*wi;
            float vi = xr*wi + xi*wr;
            float u0r = re[a0], u0i = im[a0];
            re[a0] = u0r + vr; im[a0] = u0i + vi;
            re[a1] = u0r - vr; im[a1] = u0i - vi;
        }
        __syncthreads();
    }
}

__global__ __launch_bounds__(256) void khat_kernel(const float* __restrict__ ker,
                                                   float2* __restrict__ Khat){
    __shared__ float re[64*65];
    __shared__ float im[64*65];
    __shared__ float twr[64], twi[64];
    int tid = threadIdx.x;
    int c = blockIdx.x;

    build_tw64(twr, twi, tid);
    #pragma unroll
    for (int q = 0; q < 16; q++){
        int idx = tid + q*256;
        re[(idx>>6)*65 + (idx&63)] = 0.f;
        im[(idx>>6)*65 + (idx&63)] = 0.f;
    }
    __syncthreads();
    for (int idx = tid; idx < 225; idx += 256){
        int i = idx / 15, j = idx - i*15;
        re[(24+i)*65 + (24+j)] = ker[c*225 + idx];
    }
    fft64_all<1,65>(re, im, twr, twi, tid);
    fft64_all<65,1>(re, im, twr, twi, tid);

    for (int idx = tid; idx < 64*WF; idx += 256){
        int fh = idx / WF, wf = idx - fh*WF;
        Khat[((size_t)wf*64 + fh)*64 + c] = make_float2(re[fh*65 + wf], im[fh*65 + wf]);
    }
}

// ---------------------------------------------------------------------------
extern "C" void kernel_launch(void* const* d_in, const int* in_sizes, int n_in,
                              void* d_out, int out_size, void* d_ws, size_t ws_size,
                              hipStream_t stream)
{
    const float* x   = (const float*)d_in[0];   // (2,64,64,64,64)
    const float* ker = (const float*)d_in[1];   // (64,15,15)
    float* out = (float*)d_out;                 // (2,64,64,64,64)

    char* ws = (char*)d_ws;
    float2*  Khat = (float2*)ws;                            //  1,081,344 B
    __half2* A2   = (__half2*)(ws + 1081344);               // 69,206,016 B
    __half2* Lc   = (__half2*)(ws + 1081344 + 69206016);    //  8,650,752 B
    __half2* Cin  = (__half2*)(ws + 1081344 + 69206016 + 8650752); // 8,650,752 B

    khat_kernel<<<64, 256, 0, stream>>>(ker, Khat);
    k1_row_fwd<<<8192, 256, 0, stream>>>(x, A2);
    kA<<<4224, 64, 0, stream>>>(Khat, A2, Lc);
    kB<<<PBINS/256, 256, 0, stream>>>(Khat, Lc, Cin);
    kC<<<4224, 64, 0, stream>>>(Khat, Cin, A2);
    k5_row_inv<<<8192, 256, 0, stream>>>(A2, out);
}